// Round 1
// baseline (629.265 us; speedup 1.0000x reference)
//
#include <hip/hip_runtime.h>

#define MR 50176        // B_*N = 1024*49 rows
#define DIMC 512
#define NWIN 49
#define NBATCH 1024
#define NHEADS 16
#define ATTN_SCALE 0.17677669529663689f  // 32^-0.5

typedef short bf16x8 __attribute__((ext_vector_type(8)));
typedef float f32x4 __attribute__((ext_vector_type(4)));
typedef unsigned int u32;

__device__ __forceinline__ unsigned short f2bf(float f) {
  union { float f; u32 u; } v; v.f = f;
  u32 u = v.u;
  u += 0x7FFFu + ((u >> 16) & 1u);   // round-to-nearest-even
  return (unsigned short)(u >> 16);
}
__device__ __forceinline__ float bits_f(u32 u) {
  union { u32 u; float f; } v; v.u = u; return v.f;
}

// Packed-swizzled bf16 layout (16B chunks, XOR by row&7) — see R3.
__device__ __forceinline__ size_t pk_chunk(int r, int c) {
  return (((size_t)(r >> 3) * 8 + (c >> 3)) * 64 +
          ((r & 7) * 8 + ((c & 7) ^ (r & 7)))) << 4;
}

typedef const __attribute__((address_space(1))) u32* gp_t;
typedef __attribute__((address_space(3))) u32* lp_t;
__device__ __forceinline__ void glds16(const void* g, void* l) {
  __builtin_amdgcn_global_load_lds((gp_t)g, (lp_t)l, 16, 0, 0);
}

// ---------------------------------------------------------------------------
// fp32 [rows][512] -> packed bf16; up to 3 inputs in one dispatch (grid.y).
// ---------------------------------------------------------------------------
__global__ __launch_bounds__(256) void conv_pack3(
    const float* __restrict__ X0, const float* __restrict__ X1,
    const float* __restrict__ X2, short* __restrict__ P0,
    short* __restrict__ P1, short* __restrict__ P2) {
  const float* X = (blockIdx.y == 0) ? X0 : (blockIdx.y == 1) ? X1 : X2;
  short* Xp = (blockIdx.y == 0) ? P0 : (blockIdx.y == 1) ? P1 : P2;
  const int tid = blockIdx.x * 256 + threadIdx.x;
  const int li = tid & 63, gl = tid >> 6;
  const int kline = gl & 7, group = gl >> 3;
  const int rr = li >> 3, pp = li & 7;
  const int row = group * 8 + rr;
  const int k = kline * 64 + ((pp ^ rr) << 3);
  const float* src = X + (size_t)row * DIMC + k;
  const float4 a = *(const float4*)src;
  const float4 b = *(const float4*)(src + 4);
  u32 w0 = (u32)f2bf(a.x) | ((u32)f2bf(a.y) << 16);
  u32 w1 = (u32)f2bf(a.z) | ((u32)f2bf(a.w) << 16);
  u32 w2 = (u32)f2bf(b.x) | ((u32)f2bf(b.y) << 16);
  u32 w3 = (u32)f2bf(b.z) | ((u32)f2bf(b.w) << 16);
  ((uint4*)Xp)[tid] = make_uint4(w0, w1, w2, w3);
}

// ---------------------------------------------------------------------------
// 5 weight slices -> one packed bf16 [2560][512] (k,q,v,g,proj transposed).
// ---------------------------------------------------------------------------
__global__ __launch_bounds__(256) void prep_w_pack(
    const float* __restrict__ Wqkv, const float* __restrict__ Wqkv2,
    const float* __restrict__ Wgw, const float* __restrict__ Wproj,
    short* __restrict__ Wp) {
  const int tid = blockIdx.x * 256 + threadIdx.x;   // 163840 total
  const int li = tid & 63, gl = tid >> 6;
  const int kline = gl & 7, group = gl >> 3;
  const int rr = li >> 3, pp = li & 7;
  const int row = group * 8 + rr;                    // 0..2559
  const int k = kline * 64 + ((pp ^ rr) << 3);
  const int n = row & 511, mat = row >> 9;
  const float* W; int ldw, col;
  if (mat == 0)      { W = Wqkv;  ldw = 1536; col = 512 + n; }
  else if (mat == 1) { W = Wqkv2; ldw = 1536; col = n; }
  else if (mat == 2) { W = Wqkv2; ldw = 1536; col = 1024 + n; }
  else if (mat == 3) { W = Wgw;   ldw = 512;  col = n; }
  else               { W = Wproj; ldw = 512;  col = n; }
  unsigned short h[8];
#pragma unroll
  for (int j = 0; j < 8; ++j) h[j] = f2bf(W[(size_t)(k + j) * ldw + col]);
  u32 w0 = (u32)h[0] | ((u32)h[1] << 16);
  u32 w1 = (u32)h[2] | ((u32)h[3] << 16);
  u32 w2 = (u32)h[4] | ((u32)h[5] << 16);
  u32 w3 = (u32)h[6] | ((u32)h[7] << 16);
  ((uint4*)Wp)[tid] = make_uint4(w0, w1, w2, w3);
}

// ---------------------------------------------------------------------------
// 256x256-tile 8-phase GEMM (T2+T3+T4+T5). 512 threads = 2x4 waves, each wave
// owns a 128x64 C sub-tile. LDS = 2 K-tile slots x (A 32KB + B 32KB) = 128KB.
// K-loop: per K-tile (BK=64), 4 quadrant phases, each {ds_read frag subtile |
// stage 1 half-tile via global_load_lds | barrier | setprio+16 MFMA | barrier}.
// Counted s_waitcnt vmcnt(4) once per K-tile (2 half-tiles stay in flight).
//
// Staged "parts" are quadrant-aligned regions so WAR is safe with 2 slots:
//   A part p: tile rows {p*64..p*64+63, 128+p*64..128+p*64+63}
//   B part p: tile cols {wn*64+p*32..+31 for wn=0..3}
// Part schedule for K-tile c (phase = 4c+q):  A1(c+1)@q0, B0(c+1)@q1,
// A0(c+2)@q2, B1(c+2)@q3 — each lands >=1 barrier after its region's last read.
// ---------------------------------------------------------------------------
struct GemmCfg {
  const short* A[4];
  const float* bias[4];
  short* out[4];
  int wrow0[4];
};

template <int LBX, bool OUT_F32>
__global__ __launch_bounds__(512, 2) void gemm8p(
    GemmCfg cfg, const short* __restrict__ Wp, float* __restrict__ outf) {
  __shared__ short As[2][16384];   // [slot][2 parts x 16 chunk-blocks x 512]
  __shared__ short Bs[2][16384];

  const int t = threadIdx.x, w = t >> 6, lane = t & 63;
  const int l15 = lane & 15, q = lane >> 4;
  const int wm = w >> 2, wn = w & 3;            // 2 x 4 wave grid
  const int r7 = l15 & 7, hi8 = l15 >> 3;

  // XCD-swizzled flat id: all LBX col/unit-tiles of one mtile on one XCD.
  const int id = blockIdx.x;
  const int spx = gridDim.x >> 3;               // grid % 8 == 0 always
  const int flat = (id & 7) * spx + (id >> 3);
  const int bx = flat & ((1 << LBX) - 1);
  const int mtile = flat >> LBX;
  const int unit = bx >> 1, sub = bx & 1;
  const int row0 = mtile * 256;
  const int col0 = sub * 256;
  const short* Ap = cfg.A[unit];
  const float* bias = cfg.bias[unit];
  short* outb = cfg.out[unit];
  const int nw0 = cfg.wrow0[unit] + sub * 256;

  // pk inner chunk offsets for k-chunks (ks*4+q) ^ r7
  const int in0 = (r7 * 8 + (q ^ r7)) << 4;
  const int in1 = (r7 * 8 + ((4 + q) ^ r7)) << 4;

  // stage one half-tile: pt 0/1 = A part, 2/3 = B part. 2 glds16/thread.
  auto stage = [&](int pt, int c) {
    if (c >= 8) return;
    const int slot = c & 1;
#pragma unroll
    for (int jj = 0; jj < 2; ++jj) {
      const int cb = w * 2 + jj;                // wave-uniform chunk-block
      if (pt < 2) {
        const int rowblk = ((cb & 8) ? 16 : 0) + pt * 8 + (cb & 7);
        const char* ga = (const char*)Ap +
            ((((size_t)(row0 >> 3) + rowblk) * 8 + c) << 10) +
            (size_t)lane * 16;
        glds16(ga, (char*)&As[slot][0] + (((pt << 4) + cb) << 10));
      } else {
        const int p = pt - 2;
        const int colblk = ((cb >> 2) << 3) + p * 4 + (cb & 3);
        const char* gb = (const char*)Wp +
            ((((size_t)(nw0 >> 3) + colblk) * 8 + c) << 10) +
            (size_t)lane * 16;
        glds16(gb, (char*)&Bs[slot][0] + (((p << 4) + cb) << 10));
      }
    }
  };

  f32x4 acc[8][4];
#pragma unroll
  for (int i = 0; i < 8; ++i)
#pragma unroll
    for (int j = 0; j < 4; ++j) acc[i][j] = {0.f, 0.f, 0.f, 0.f};

  // Prologue: K-tile0 all 4 parts + K-tile1 first 2 parts (issue order = the
  // steady-state stream: A0,B1,A1,B0 | A0,B1). Wait K-tile0 (keep 2 in flight).
  stage(0, 0); stage(3, 0); stage(1, 0); stage(2, 0);
  stage(0, 1); stage(3, 1);
  asm volatile("s_waitcnt vmcnt(4)" ::: "memory");
  asm volatile("s_barrier" ::: "memory");

  for (int c = 0; c < 8; ++c) {
    const char* Ab = (const char*)&As[c & 1][0];
    const char* Bb = (const char*)&Bs[c & 1][0];
    bf16x8 af[4][2], bfA[2][2], bfB[2][2];

    // ---- phase q0: quadrant (rl=0, cl=0) — 12 ds_read ----
#pragma unroll
    for (int i = 0; i < 4; ++i) {
      const int o = (wm * 8 + i * 2 + hi8) << 10;
      af[i][0] = *(const bf16x8*)(Ab + o + in0);
      af[i][1] = *(const bf16x8*)(Ab + o + in1);
    }
#pragma unroll
    for (int j = 0; j < 2; ++j) {
      const int o = (wn * 4 + j * 2 + hi8) << 10;
      bfA[j][0] = *(const bf16x8*)(Bb + o + in0);
      bfA[j][1] = *(const bf16x8*)(Bb + o + in1);
    }
    stage(1, c + 1);
    asm volatile("s_barrier" ::: "memory");
    __builtin_amdgcn_s_setprio(1);
#pragma unroll
    for (int i = 0; i < 4; ++i)
#pragma unroll
      for (int j = 0; j < 2; ++j) {
        acc[i][j] = __builtin_amdgcn_mfma_f32_16x16x32_bf16(
            af[i][0], bfA[j][0], acc[i][j], 0, 0, 0);
        acc[i][j] = __builtin_amdgcn_mfma_f32_16x16x32_bf16(
            af[i][1], bfA[j][1], acc[i][j], 0, 0, 0);
      }
    __builtin_amdgcn_s_setprio(0);
    asm volatile("s_barrier" ::: "memory");

    // ---- phase q1: quadrant (0,1) — 4 ds_read (reuse af) ----
#pragma unroll
    for (int j = 0; j < 2; ++j) {
      const int o = (16 + wn * 4 + j * 2 + hi8) << 10;
      bfB[j][0] = *(const bf16x8*)(Bb + o + in0);
      bfB[j][1] = *(const bf16x8*)(Bb + o + in1);
    }
    stage(2, c + 1);
    asm volatile("s_barrier" ::: "memory");
    __builtin_amdgcn_s_setprio(1);
#pragma unroll
    for (int i = 0; i < 4; ++i)
#pragma unroll
      for (int j = 0; j < 2; ++j) {
        acc[i][2 + j] = __builtin_amdgcn_mfma_f32_16x16x32_bf16(
            af[i][0], bfB[j][0], acc[i][2 + j], 0, 0, 0);
        acc[i][2 + j] = __builtin_amdgcn_mfma_f32_16x16x32_bf16(
            af[i][1], bfB[j][1], acc[i][2 + j], 0, 0, 0);
      }
    __builtin_amdgcn_s_setprio(0);
    asm volatile("s_barrier" ::: "memory");

    // ---- phase q2: quadrant (1,1) — 8 ds_read (reuse bfB) ----
#pragma unroll
    for (int i = 0; i < 4; ++i) {
      const int o = (16 + wm * 8 + i * 2 + hi8) << 10;
      af[i][0] = *(const bf16x8*)(Ab + o + in0);
      af[i][1] = *(const bf16x8*)(Ab + o + in1);
    }
    stage(0, c + 2);
    asm volatile("s_barrier" ::: "memory");
    __builtin_amdgcn_s_setprio(1);
#pragma unroll
    for (int i = 0; i < 4; ++i)
#pragma unroll
      for (int j = 0; j < 2; ++j) {
        acc[4 + i][2 + j] = __builtin_amdgcn_mfma_f32_16x16x32_bf16(
            af[i][0], bfB[j][0], acc[4 + i][2 + j], 0, 0, 0);
        acc[4 + i][2 + j] = __builtin_amdgcn_mfma_f32_16x16x32_bf16(
            af[i][1], bfB[j][1], acc[4 + i][2 + j], 0, 0, 0);
      }
    __builtin_amdgcn_s_setprio(0);
    asm volatile("s_barrier" ::: "memory");

    // ---- phase q3: quadrant (1,0) — 0 ds_read (reuse af, bfA) ----
    stage(3, c + 2);
    asm volatile("s_barrier" ::: "memory");
    __builtin_amdgcn_s_setprio(1);
#pragma unroll
    for (int i = 0; i < 4; ++i)
#pragma unroll
      for (int j = 0; j < 2; ++j) {
        acc[4 + i][j] = __builtin_amdgcn_mfma_f32_16x16x32_bf16(
            af[i][0], bfA[j][0], acc[4 + i][j], 0, 0, 0);
        acc[4 + i][j] = __builtin_amdgcn_mfma_f32_16x16x32_bf16(
            af[i][1], bfA[j][1], acc[4 + i][j], 0, 0, 0);
      }
    __builtin_amdgcn_s_setprio(0);
    // K-tile boundary: everything through B0(c+1) must be landed before any
    // wave reads slot (c+1)&1. Outstanding afterwards: A0(c+2),B1(c+2) = 4.
    if (c < 6)
      asm volatile("s_waitcnt vmcnt(4)" ::: "memory");
    else
      asm volatile("s_waitcnt vmcnt(0)" ::: "memory");
    asm volatile("s_barrier" ::: "memory");
  }

  // Epilogue: wave's 128x64 C sub-tile.
#pragma unroll
  for (int ci = 0; ci < 4; ++ci) {
    const int C = col0 + wn * 64 + (ci >> 1) * 32 + (ci & 1) * 16 + l15;
    const float bv = bias[C];
#pragma unroll
    for (int ri = 0; ri < 8; ++ri) {
      const int R = row0 + wm * 128 + (ri >> 2) * 64 + (ri & 3) * 16 + q * 4;
#pragma unroll
      for (int r = 0; r < 4; ++r) {
        const float val = acc[ri][ci][r] + bv;
        if constexpr (OUT_F32)
          outf[(size_t)(R + r) * DIMC + C] = val;
        else
          *(short*)((char*)outb + pk_chunk(R + r, C >> 3) + ((C & 7) << 1)) =
              (short)f2bf(val);
      }
    }
  }
}

// ---------------------------------------------------------------------------
// MFMA attention, one window per wave (unchanged; packed I/O).
// ---------------------------------------------------------------------------
__global__ __launch_bounds__(256) void attn_mfma(
    const short* __restrict__ kbuf, const short* __restrict__ qbuf,
    const short* __restrict__ vbuf, const short* __restrict__ gbuf,
    const float* __restrict__ a_scalar, short* __restrict__ obuf) {
  __shared__ short pls[4][64 * 40];
  __shared__ short vls[4][32 * 72];

  const int t = threadIdx.x;
  const int w = t >> 6, lane = t & 63;
  const int l15 = lane & 15, q = lane >> 4;
  const int wid = blockIdx.x * 4 + w;
  const int b = wid >> 4, h = wid & 15;
  const int row0 = b * NWIN;
  const float aval = a_scalar[0];
  short* P = pls[w];
  short* VT = vls[w];

#pragma unroll
  for (int it = 0; it < 5; ++it) {
    int off = (it * 64 + lane) * 8;
    if (off < 32 * 72) *(uint4*)&VT[off] = make_uint4(0u, 0u, 0u, 0u);
  }

  bf16x8 kf[4];
#pragma unroll
  for (int mj = 0; mj < 4; ++mj) {
    int m = mj * 16 + l15; if (m > 48) m = 48;
    kf[mj] = *(const bf16x8*)((const char*)kbuf + pk_chunk(row0 + m, h * 4 + q));
  }
  bf16x8 qf[4];
#pragma unroll
  for (int mi = 0; mi < 4; ++mi) {
    int n = mi * 16 + l15; if (n > 48) n = 48;
    const size_t off = pk_chunk(row0 + n, h * 4 + q);
    uint4 qa = *(const uint4*)((const char*)qbuf + off);
    uint4 ga = *(const uint4*)((const char*)gbuf + off);
    u32* qa_ = (u32*)&qa;
    u32* ga_ = (u32*)&ga;
    uint4 res; u32* r_ = (u32*)&res;
#pragma unroll
    for (int jj = 0; jj < 4; ++jj) {
      float lo = bits_f(qa_[jj] << 16) * bits_f(ga_[jj] << 16);
      float hi = bits_f(qa_[jj] & 0xffff0000u) * bits_f(ga_[jj] & 0xffff0000u);
      r_[jj] = (u32)f2bf(lo) | ((u32)f2bf(hi) << 16);
    }
    qf[mi] = *(bf16x8*)&res;
  }
#pragma unroll
  for (int it = 0; it < 4; ++it) {
    int chunk = it * 64 + lane;
    if (chunk < 196) {
      int n = chunk >> 2, dcq = chunk & 3;
      uint4 v = *(const uint4*)((const char*)vbuf + pk_chunk(row0 + n, h * 4 + dcq));
      const short* vs = (const short*)&v;
#pragma unroll
      for (int j = 0; j < 8; ++j) VT[(dcq * 8 + j) * 72 + n] = vs[j];
    }
  }

  f32x4 s[4][4];
#pragma unroll
  for (int mi = 0; mi < 4; ++mi)
#pragma unroll
    for (int nj = 0; nj < 4; ++nj) {
      f32x4 z = {0.f, 0.f, 0.f, 0.f};
      s[mi][nj] = __builtin_amdgcn_mfma_f32_16x16x32_bf16(qf[mi], kf[nj], z, 0, 0, 0);
    }

#pragma unroll
  for (int mi = 0; mi < 4; ++mi)
#pragma unroll
    for (int nj = 0; nj < 4; ++nj) {
      const bool valid = (nj * 16 + l15) < NWIN;
#pragma unroll
      for (int r = 0; r < 4; ++r)
        s[mi][nj][r] = valid ? __expf(ATTN_SCALE * s[mi][nj][r]) : 0.f;
    }

  float lsum[4][4];
#pragma unroll
  for (int mi = 0; mi < 4; ++mi)
#pragma unroll
    for (int r = 0; r < 4; ++r) {
      float part = s[mi][0][r] + s[mi][1][r] + s[mi][2][r] + s[mi][3][r];
      part += __shfl_xor(part, 1, 64);
      part += __shfl_xor(part, 2, 64);
      part += __shfl_xor(part, 4, 64);
      part += __shfl_xor(part, 8, 64);
      lsum[mi][r] = part;
    }

  f32x4 o[4][2];
#pragma unroll
  for (int mi = 0; mi < 4; ++mi)
#pragma unroll
    for (int dj = 0; dj < 2; ++dj) o[mi][dj] = {0.f, 0.f, 0.f, 0.f};

#pragma unroll
  for (int c = 0; c < 2; ++c) {
#pragma unroll
    for (int mi = 0; mi < 4; ++mi)
#pragma unroll
      for (int njh = 0; njh < 2; ++njh) {
        const int nj = c * 2 + njh;
        const int m = nj * 16 + l15;
#pragma unroll
        for (int r = 0; r < 4; ++r) {
          const int n = mi * 16 + q * 4 + r;
          float val = s[mi][nj][r];
          if (m == n) val += aval * lsum[mi][r];
          P[n * 40 + njh * 16 + l15] = (short)f2bf(val);
        }
      }
    bf16x8 bfr[2];
#pragma unroll
    for (int dj = 0; dj < 2; ++dj)
      bfr[dj] = *(const bf16x8*)&VT[(dj * 16 + l15) * 72 + c * 32 + q * 8];
#pragma unroll
    for (int mi = 0; mi < 4; ++mi) {
      bf16x8 af = *(const bf16x8*)&P[(mi * 16 + l15) * 40 + q * 8];
#pragma unroll
      for (int dj = 0; dj < 2; ++dj)
        o[mi][dj] = __builtin_amdgcn_mfma_f32_16x16x32_bf16(af, bfr[dj],
                                                            o[mi][dj], 0, 0, 0);
    }
  }

#pragma unroll
  for (int mi = 0; mi < 4; ++mi)
#pragma unroll
    for (int r = 0; r < 4; ++r) {
      const int n = mi * 16 + q * 4 + r;
      if (n < NWIN) {
        const float rl = 1.0f / lsum[mi][r];
#pragma unroll
        for (int dj = 0; dj < 2; ++dj) {
          const int d = dj * 16 + l15;
          *(short*)((char*)obuf + pk_chunk(row0 + n, h * 4 + (d >> 3)) +
                    ((d & 7) << 1)) = (short)f2bf(o[mi][dj][r] * rl);
        }
      }
    }
}

// ---------------------------------------------------------------------------
extern "C" void kernel_launch(void* const* d_in, const int* in_sizes, int n_in,
                              void* d_out, int out_size, void* d_ws,
                              size_t ws_size, hipStream_t stream) {
  const float* x     = (const float*)d_in[0];
  const float* x2    = (const float*)d_in[1];
  const float* x3    = (const float*)d_in[2];
  const float* Wqkv  = (const float*)d_in[3];
  const float* bqkv  = (const float*)d_in[4];
  const float* Wqkv2 = (const float*)d_in[5];
  const float* bqkv2 = (const float*)d_in[6];
  const float* Wgw   = (const float*)d_in[7];
  const float* bgw   = (const float*)d_in[8];
  const float* Wproj = (const float*)d_in[9];
  const float* bproj = (const float*)d_in[10];
  const float* a     = (const float*)d_in[11];

  char* ws = (char*)d_ws;
  const size_t WTSZ = (size_t)2560 * DIMC * sizeof(short);   // 2.62 MB
  const size_t BSZ  = (size_t)MR * DIMC * sizeof(short);     // 51.4 MB
  short* wt_all = (short*)ws;

  prep_w_pack<<<640, 256, 0, stream>>>(Wqkv, Wqkv2, Wgw, Wproj, wt_all);

  const int convg = MR * DIMC / 8 / 256;        // 12544

  if (ws_size >= WTSZ + 7 * BSZ) {
    // ---------------- fused path (362 MB workspace) ----------------
    short* xp   = (short*)(ws + WTSZ);
    short* x2p  = (short*)(ws + WTSZ + BSZ);
    short* x3p  = (short*)(ws + WTSZ + 2 * BSZ);
    short* kbuf = (short*)(ws + WTSZ + 3 * BSZ);
    short* qbuf = (short*)(ws + WTSZ + 4 * BSZ);
    short* vbuf = (short*)(ws + WTSZ + 5 * BSZ);
    short* gbuf = (short*)(ws + WTSZ + 6 * BSZ);
    short* obuf = xp;  // xp dead after stage-1

    conv_pack3<<<dim3(convg, 3), 256, 0, stream>>>(x, x2, x3, xp, x2p, x3p);

    GemmCfg s1;
    s1.A[0] = xp;  s1.A[1] = x3p; s1.A[2] = x3p; s1.A[3] = x2p;
    s1.bias[0] = bqkv + 512; s1.bias[1] = bqkv2;
    s1.bias[2] = bqkv2 + 1024; s1.bias[3] = bgw;
    s1.out[0] = kbuf; s1.out[1] = qbuf; s1.out[2] = vbuf; s1.out[3] = gbuf;
    s1.wrow0[0] = 0; s1.wrow0[1] = 512; s1.wrow0[2] = 1024; s1.wrow0[3] = 1536;
    // 8 bx (4 units x 2 col-tiles) x 196 mtiles = 1568 blocks
    gemm8p<3, false><<<1568, 512, 0, stream>>>(s1, wt_all, nullptr);

    attn_mfma<<<(NBATCH * NHEADS) / 4, 256, 0, stream>>>(kbuf, qbuf, vbuf,
                                                         gbuf, a, obuf);

    GemmCfg pj = {};
    pj.A[0] = obuf; pj.bias[0] = bproj; pj.out[0] = nullptr; pj.wrow0[0] = 2048;
    gemm8p<1, true><<<392, 512, 0, stream>>>(pj, wt_all, (float*)d_out);
  } else {
    // ---------------- serial fallback (259.5 MB) ----------------
    short* cb   = (short*)(ws + WTSZ);
    short* kbuf = (short*)(ws + WTSZ + BSZ);
    short* qbuf = (short*)(ws + WTSZ + 2 * BSZ);
    short* vbuf = (short*)(ws + WTSZ + 3 * BSZ);
    short* gbuf = (short*)(ws + WTSZ + 4 * BSZ);
    short* obuf = cb;

    conv_pack3<<<dim3(convg, 1), 256, 0, stream>>>(x, x, x, cb, cb, cb);
    GemmCfg ck = {};
    ck.A[0] = cb; ck.bias[0] = bqkv + 512; ck.out[0] = kbuf; ck.wrow0[0] = 0;
    gemm8p<1, false><<<392, 512, 0, stream>>>(ck, wt_all, nullptr);

    conv_pack3<<<dim3(convg, 1), 256, 0, stream>>>(x3, x3, x3, cb, cb, cb);
    GemmCfg cqv = {};
    cqv.A[0] = cb; cqv.A[1] = cb;
    cqv.bias[0] = bqkv2; cqv.bias[1] = bqkv2 + 1024;
    cqv.out[0] = qbuf; cqv.out[1] = vbuf;
    cqv.wrow0[0] = 512; cqv.wrow0[1] = 1024;
    gemm8p<2, false><<<784, 512, 0, stream>>>(cqv, wt_all, nullptr);

    conv_pack3<<<dim3(convg, 1), 256, 0, stream>>>(x2, x2, x2, cb, cb, cb);
    GemmCfg cg = {};
    cg.A[0] = cb; cg.bias[0] = bgw; cg.out[0] = gbuf; cg.wrow0[0] = 1536;
    gemm8p<1, false><<<392, 512, 0, stream>>>(cg, wt_all, nullptr);

    attn_mfma<<<(NBATCH * NHEADS) / 4, 256, 0, stream>>>(kbuf, qbuf, vbuf,
                                                         gbuf, a, obuf);

    GemmCfg pj = {};
    pj.A[0] = obuf; pj.bias[0] = bproj; pj.wrow0[0] = 2048;
    gemm8p<1, true><<<392, 512, 0, stream>>>(pj, wt_all, (float*)d_out);
  }
}

// Round 3
// 612.745 us; speedup vs baseline: 1.0270x; 1.0270x over previous
//
#include <hip/hip_runtime.h>

#define MR 50176        // B_*N = 1024*49 rows
#define DIMC 512
#define NWIN 49
#define NBATCH 1024
#define NHEADS 16
#define ATTN_SCALE 0.17677669529663689f  // 32^-0.5

typedef short bf16x8 __attribute__((ext_vector_type(8)));
typedef float f32x4 __attribute__((ext_vector_type(4)));
typedef unsigned int u32;

__device__ __forceinline__ unsigned short f2bf(float f) {
  union { float f; u32 u; } v; v.f = f;
  u32 u = v.u;
  u += 0x7FFFu + ((u >> 16) & 1u);   // round-to-nearest-even
  return (unsigned short)(u >> 16);
}
__device__ __forceinline__ float bits_f(u32 u) {
  union { u32 u; float f; } v; v.u = u; return v.f;
}

// Packed-swizzled bf16 layout (16B chunks, XOR by row&7).
__device__ __forceinline__ size_t pk_chunk(int r, int c) {
  return (((size_t)(r >> 3) * 8 + (c >> 3)) * 64 +
          ((r & 7) * 8 + ((c & 7) ^ (r & 7)))) << 4;
}

typedef const __attribute__((address_space(1))) u32* gp_t;
typedef __attribute__((address_space(3))) u32* lp_t;
__device__ __forceinline__ void glds16(const void* g, void* l) {
  __builtin_amdgcn_global_load_lds((gp_t)g, (lp_t)l, 16, 0, 0);
}

// ---------------------------------------------------------------------------
// 5 weight slices -> one packed bf16 [2560][512] (k,q,v,g,proj transposed).
// ---------------------------------------------------------------------------
__global__ __launch_bounds__(256) void prep_w_pack(
    const float* __restrict__ Wqkv, const float* __restrict__ Wqkv2,
    const float* __restrict__ Wgw, const float* __restrict__ Wproj,
    short* __restrict__ Wp) {
  const int tid = blockIdx.x * 256 + threadIdx.x;   // 163840 total
  const int li = tid & 63, gl = tid >> 6;
  const int kline = gl & 7, group = gl >> 3;
  const int rr = li >> 3, pp = li & 7;
  const int row = group * 8 + rr;                    // 0..2559
  const int k = kline * 64 + ((pp ^ rr) << 3);
  const int n = row & 511, mat = row >> 9;
  const float* W; int ldw, col;
  if (mat == 0)      { W = Wqkv;  ldw = 1536; col = 512 + n; }
  else if (mat == 1) { W = Wqkv2; ldw = 1536; col = n; }
  else if (mat == 2) { W = Wqkv2; ldw = 1536; col = 1024 + n; }
  else if (mat == 3) { W = Wgw;   ldw = 512;  col = n; }
  else               { W = Wproj; ldw = 512;  col = n; }
  unsigned short h[8];
#pragma unroll
  for (int j = 0; j < 8; ++j) h[j] = f2bf(W[(size_t)(k + j) * ldw + col]);
  u32 w0 = (u32)h[0] | ((u32)h[1] << 16);
  u32 w1 = (u32)h[2] | ((u32)h[3] << 16);
  u32 w2 = (u32)h[4] | ((u32)h[5] << 16);
  u32 w3 = (u32)h[6] | ((u32)h[7] << 16);
  ((uint4*)Wp)[tid] = make_uint4(w0, w1, w2, w3);
}

// ---------------------------------------------------------------------------
// Multi-output GEMM, 128x128 tile, 2 blocks/CU, XCD-swizzled 1D grid.
// CONVA=true: A is raw fp32 [rows][512]; staging converts fp32->bf16 in regs
// and ds_writes the same XOR-packed LDS image glds16 would have produced —
// this fuses the old conv_pack3 kernel into the GEMM (deletes a full
// 308MB-read + 154MB-write + 131MB-reread HBM round-trip).
// Pipelined staging (CONVA): A-loads(kt+1) issued after A(kt) consumed;
// vmcnt(4) drains A(kt) (4 B-glds stay in flight); vmcnt(8)+lgkm(0) drains
// B(kt) before the compute barrier (8 A(kt+1) stay in flight). Never a full
// vmcnt(0) drain mid-loop.
// ---------------------------------------------------------------------------
struct GemmCfg {
  const short* A[4];
  const float* Af[4];
  const float* bias[4];
  short* out[4];
  int wrow0[4];
};

template <int LNX, bool OUT_F32, bool CONVA>
__global__ __launch_bounds__(256) void gemm_glds(
    GemmCfg cfg, const short* __restrict__ Wp, float* __restrict__ outf) {
  __shared__ short As[128 * 64];
  __shared__ short Bs[128 * 64];

  const int t = threadIdx.x, w = t >> 6, lane = t & 63;
  const int l15 = lane & 15, q = lane >> 4;
  const int wm = w >> 1, wn = w & 1;
  const int id = blockIdx.x;
  const int xcd = id & 7, slot = id >> 3;
  const int bx = slot & ((1 << LNX) - 1);
  const int y = xcd + ((slot >> LNX) << 3);
  const int row0 = y * 128;
  const int unit = bx >> 2, sub = bx & 3;
  const float* bias = cfg.bias[unit];
  short* outb = cfg.out[unit];
  const int nw0 = cfg.wrow0[unit] + sub * 128;
  const int col0 = sub * 128;

  f32x4 acc[4][4];
#pragma unroll
  for (int i = 0; i < 4; ++i)
#pragma unroll
    for (int j = 0; j < 4; ++j) acc[i][j] = {0.f, 0.f, 0.f, 0.f};

  const size_t lb = (size_t)lane * 16;
  const int r7 = l15 & 7, hi8 = l15 >> 3;

  if constexpr (CONVA) {
    const int rr = lane >> 3, pp = lane & 7;
    const float* abase =
        cfg.Af[unit] + (size_t)(row0 + w * 32 + rr) * DIMC + ((pp ^ rr) << 3);
    float4 ar[4][2];
#pragma unroll
    for (int jj = 0; jj < 4; ++jj) {
      const float* s = abase + (size_t)jj * 8 * DIMC;
      ar[jj][0] = *(const float4*)s;
      ar[jj][1] = *(const float4*)(s + 4);
    }
    for (int kt = 0; kt < 8; ++kt) {
      asm volatile("s_barrier" ::: "memory");     // LDS free (prev reads done)
#pragma unroll
      for (int jj = 0; jj < 4; ++jj) {
        const int rg = w * 4 + jj;
        const char* gb =
            (const char*)Wp + ((((size_t)(nw0 >> 3) + rg) * 8 + kt) << 10);
        glds16(gb + lb, &Bs[(size_t)rg << 9]);
      }
      // drain the 8 A-loads of tile kt (4 B-glds remain outstanding)
      asm volatile("s_waitcnt vmcnt(4)" ::: "memory");
#pragma unroll
      for (int jj = 0; jj < 4; ++jj) {
        u32 w0 = (u32)f2bf(ar[jj][0].x) | ((u32)f2bf(ar[jj][0].y) << 16);
        u32 w1 = (u32)f2bf(ar[jj][0].z) | ((u32)f2bf(ar[jj][0].w) << 16);
        u32 w2 = (u32)f2bf(ar[jj][1].x) | ((u32)f2bf(ar[jj][1].y) << 16);
        u32 w3 = (u32)f2bf(ar[jj][1].z) | ((u32)f2bf(ar[jj][1].w) << 16);
        *(uint4*)&As[(((size_t)(w * 4 + jj)) << 9) + (size_t)lane * 8] =
            make_uint4(w0, w1, w2, w3);
      }
      if (kt < 7) {
        // prefetch A(kt+1): full iteration of distance before consumption
#pragma unroll
        for (int jj = 0; jj < 4; ++jj) {
          const float* s = abase + (size_t)jj * 8 * DIMC + (kt + 1) * 64;
          ar[jj][0] = *(const float4*)s;
          ar[jj][1] = *(const float4*)(s + 4);
        }
        // drain B(kt) (oldest 4); keep the 8 A(kt+1) in flight
        asm volatile("s_waitcnt vmcnt(8) lgkmcnt(0)" ::: "memory");
      } else {
        asm volatile("s_waitcnt vmcnt(0) lgkmcnt(0)" ::: "memory");
      }
      asm volatile("s_barrier" ::: "memory");
#pragma unroll
      for (int s = 0; s < 2; ++s) {
        const int sw = ((s * 4 + q) ^ r7);
        const int pos = (r7 * 8 + sw) * 8;
        bf16x8 af[4], bfr[4];
#pragma unroll
        for (int i = 0; i < 4; ++i)
          af[i] = *(const bf16x8*)&As[((wm * 8 + i * 2 + hi8) << 9) + pos];
#pragma unroll
        for (int j = 0; j < 4; ++j)
          bfr[j] = *(const bf16x8*)&Bs[((wn * 8 + j * 2 + hi8) << 9) + pos];
#pragma unroll
        for (int i = 0; i < 4; ++i)
#pragma unroll
          for (int j = 0; j < 4; ++j)
            acc[i][j] = __builtin_amdgcn_mfma_f32_16x16x32_bf16(
                af[i], bfr[j], acc[i][j], 0, 0, 0);
      }
    }
  } else {
    const short* Ap = cfg.A[unit];
    for (int kt = 0; kt < 8; ++kt) {
      __syncthreads();
#pragma unroll
      for (int jj = 0; jj < 4; ++jj) {
        const int rg = w * 4 + jj;
        const char* ga =
            (const char*)Ap + ((((size_t)(row0 >> 3) + rg) * 8 + kt) << 10);
        glds16(ga + lb, &As[(size_t)rg << 9]);
        const char* gb =
            (const char*)Wp + ((((size_t)(nw0 >> 3) + rg) * 8 + kt) << 10);
        glds16(gb + lb, &Bs[(size_t)rg << 9]);
      }
      __syncthreads();
#pragma unroll
      for (int s = 0; s < 2; ++s) {
        const int sw = ((s * 4 + q) ^ r7);
        const int pos = (r7 * 8 + sw) * 8;
        bf16x8 af[4], bfr[4];
#pragma unroll
        for (int i = 0; i < 4; ++i)
          af[i] = *(const bf16x8*)&As[((wm * 8 + i * 2 + hi8) << 9) + pos];
#pragma unroll
        for (int j = 0; j < 4; ++j)
          bfr[j] = *(const bf16x8*)&Bs[((wn * 8 + j * 2 + hi8) << 9) + pos];
#pragma unroll
        for (int i = 0; i < 4; ++i)
#pragma unroll
          for (int j = 0; j < 4; ++j)
            acc[i][j] = __builtin_amdgcn_mfma_f32_16x16x32_bf16(
                af[i], bfr[j], acc[i][j], 0, 0, 0);
      }
    }
  }

#pragma unroll
  for (int j = 0; j < 4; ++j) {
    const int C = col0 + wn * 64 + j * 16 + l15;
    const float bv = bias[C];
#pragma unroll
    for (int i = 0; i < 4; ++i) {
#pragma unroll
      for (int r = 0; r < 4; ++r) {
        const int R = row0 + wm * 64 + i * 16 + q * 4 + r;
        const float val = acc[i][j][r] + bv;
        if constexpr (OUT_F32)
          outf[(size_t)R * DIMC + C] = val;
        else
          *(short*)((char*)outb + pk_chunk(R, C >> 3) + ((C & 7) << 1)) =
              (short)f2bf(val);
      }
    }
  }
}

// ---------------------------------------------------------------------------
// MFMA attention, one window per wave (unchanged; packed I/O).
// ---------------------------------------------------------------------------
__global__ __launch_bounds__(256) void attn_mfma(
    const short* __restrict__ kbuf, const short* __restrict__ qbuf,
    const short* __restrict__ vbuf, const short* __restrict__ gbuf,
    const float* __restrict__ a_scalar, short* __restrict__ obuf) {
  __shared__ short pls[4][64 * 40];
  __shared__ short vls[4][32 * 72];

  const int t = threadIdx.x;
  const int w = t >> 6, lane = t & 63;
  const int l15 = lane & 15, q = lane >> 4;
  const int wid = blockIdx.x * 4 + w;
  const int b = wid >> 4, h = wid & 15;
  const int row0 = b * NWIN;
  const float aval = a_scalar[0];
  short* P = pls[w];
  short* VT = vls[w];

#pragma unroll
  for (int it = 0; it < 5; ++it) {
    int off = (it * 64 + lane) * 8;
    if (off < 32 * 72) *(uint4*)&VT[off] = make_uint4(0u, 0u, 0u, 0u);
  }

  bf16x8 kf[4];
#pragma unroll
  for (int mj = 0; mj < 4; ++mj) {
    int m = mj * 16 + l15; if (m > 48) m = 48;
    kf[mj] = *(const bf16x8*)((const char*)kbuf + pk_chunk(row0 + m, h * 4 + q));
  }
  bf16x8 qf[4];
#pragma unroll
  for (int mi = 0; mi < 4; ++mi) {
    int n = mi * 16 + l15; if (n > 48) n = 48;
    const size_t off = pk_chunk(row0 + n, h * 4 + q);
    uint4 qa = *(const uint4*)((const char*)qbuf + off);
    uint4 ga = *(const uint4*)((const char*)gbuf + off);
    u32* qa_ = (u32*)&qa;
    u32* ga_ = (u32*)&ga;
    uint4 res; u32* r_ = (u32*)&res;
#pragma unroll
    for (int jj = 0; jj < 4; ++jj) {
      float lo = bits_f(qa_[jj] << 16) * bits_f(ga_[jj] << 16);
      float hi = bits_f(qa_[jj] & 0xffff0000u) * bits_f(ga_[jj] & 0xffff0000u);
      r_[jj] = (u32)f2bf(lo) | ((u32)f2bf(hi) << 16);
    }
    qf[mi] = *(bf16x8*)&res;
  }
#pragma unroll
  for (int it = 0; it < 4; ++it) {
    int chunk = it * 64 + lane;
    if (chunk < 196) {
      int n = chunk >> 2, dcq = chunk & 3;
      uint4 v = *(const uint4*)((const char*)vbuf + pk_chunk(row0 + n, h * 4 + dcq));
      const short* vs = (const short*)&v;
#pragma unroll
      for (int j = 0; j < 8; ++j) VT[(dcq * 8 + j) * 72 + n] = vs[j];
    }
  }

  f32x4 s[4][4];
#pragma unroll
  for (int mi = 0; mi < 4; ++mi)
#pragma unroll
    for (int nj = 0; nj < 4; ++nj) {
      f32x4 z = {0.f, 0.f, 0.f, 0.f};
      s[mi][nj] = __builtin_amdgcn_mfma_f32_16x16x32_bf16(qf[mi], kf[nj], z, 0, 0, 0);
    }

#pragma unroll
  for (int mi = 0; mi < 4; ++mi)
#pragma unroll
    for (int nj = 0; nj < 4; ++nj) {
      const bool valid = (nj * 16 + l15) < NWIN;
#pragma unroll
      for (int r = 0; r < 4; ++r)
        s[mi][nj][r] = valid ? __expf(ATTN_SCALE * s[mi][nj][r]) : 0.f;
    }

  float lsum[4][4];
#pragma unroll
  for (int mi = 0; mi < 4; ++mi)
#pragma unroll
    for (int r = 0; r < 4; ++r) {
      float part = s[mi][0][r] + s[mi][1][r] + s[mi][2][r] + s[mi][3][r];
      part += __shfl_xor(part, 1, 64);
      part += __shfl_xor(part, 2, 64);
      part += __shfl_xor(part, 4, 64);
      part += __shfl_xor(part, 8, 64);
      lsum[mi][r] = part;
    }

  f32x4 o[4][2];
#pragma unroll
  for (int mi = 0; mi < 4; ++mi)
#pragma unroll
    for (int dj = 0; dj < 2; ++dj) o[mi][dj] = {0.f, 0.f, 0.f, 0.f};

#pragma unroll
  for (int c = 0; c < 2; ++c) {
#pragma unroll
    for (int mi = 0; mi < 4; ++mi)
#pragma unroll
      for (int njh = 0; njh < 2; ++njh) {
        const int nj = c * 2 + njh;
        const int m = nj * 16 + l15;
#pragma unroll
        for (int r = 0; r < 4; ++r) {
          const int n = mi * 16 + q * 4 + r;
          float val = s[mi][nj][r];
          if (m == n) val += aval * lsum[mi][r];
          P[n * 40 + njh * 16 + l15] = (short)f2bf(val);
        }
      }
    bf16x8 bfr[2];
#pragma unroll
    for (int dj = 0; dj < 2; ++dj)
      bfr[dj] = *(const bf16x8*)&VT[(dj * 16 + l15) * 72 + c * 32 + q * 8];
#pragma unroll
    for (int mi = 0; mi < 4; ++mi) {
      bf16x8 af = *(const bf16x8*)&P[(mi * 16 + l15) * 40 + q * 8];
#pragma unroll
      for (int dj = 0; dj < 2; ++dj)
        o[mi][dj] = __builtin_amdgcn_mfma_f32_16x16x32_bf16(af, bfr[dj],
                                                            o[mi][dj], 0, 0, 0);
    }
  }

#pragma unroll
  for (int mi = 0; mi < 4; ++mi)
#pragma unroll
    for (int r = 0; r < 4; ++r) {
      const int n = mi * 16 + q * 4 + r;
      if (n < NWIN) {
        const float rl = 1.0f / lsum[mi][r];
#pragma unroll
        for (int dj = 0; dj < 2; ++dj) {
          const int d = dj * 16 + l15;
          *(short*)((char*)obuf + pk_chunk(row0 + n, h * 4 + (d >> 3)) +
                    ((d & 7) << 1)) = (short)f2bf(o[mi][dj][r] * rl);
        }
      }
    }
}

// ---------------------------------------------------------------------------
extern "C" void kernel_launch(void* const* d_in, const int* in_sizes, int n_in,
                              void* d_out, int out_size, void* d_ws,
                              size_t ws_size, hipStream_t stream) {
  const float* x     = (const float*)d_in[0];
  const float* x2    = (const float*)d_in[1];
  const float* x3    = (const float*)d_in[2];
  const float* Wqkv  = (const float*)d_in[3];
  const float* bqkv  = (const float*)d_in[4];
  const float* Wqkv2 = (const float*)d_in[5];
  const float* bqkv2 = (const float*)d_in[6];
  const float* Wgw   = (const float*)d_in[7];
  const float* bgw   = (const float*)d_in[8];
  const float* Wproj = (const float*)d_in[9];
  const float* bproj = (const float*)d_in[10];
  const float* a     = (const float*)d_in[11];

  char* ws = (char*)d_ws;
  const size_t WTSZ = (size_t)2560 * DIMC * sizeof(short);   // 2.62 MB
  const size_t BSZ  = (size_t)MR * DIMC * sizeof(short);     // 51.4 MB
  short* wt_all = (short*)ws;

  short* kbuf = (short*)(ws + WTSZ);
  short* qbuf = (short*)(ws + WTSZ + BSZ);
  short* vbuf = (short*)(ws + WTSZ + 2 * BSZ);
  short* gbuf = (short*)(ws + WTSZ + 3 * BSZ);
  short* obuf = (short*)(ws + WTSZ + 4 * BSZ);   // 259.7 MB total

  prep_w_pack<<<640, 256, 0, stream>>>(Wqkv, Wqkv2, Wgw, Wproj, wt_all);

  // Stage 1: fused fp32->bf16 conversion inside the GEMM (conv_pack3 deleted).
  GemmCfg s1 = {};
  s1.Af[0] = x;  s1.Af[1] = x3; s1.Af[2] = x3; s1.Af[3] = x2;
  s1.bias[0] = bqkv + 512; s1.bias[1] = bqkv2;
  s1.bias[2] = bqkv2 + 1024; s1.bias[3] = bgw;
  s1.out[0] = kbuf; s1.out[1] = qbuf; s1.out[2] = vbuf; s1.out[3] = gbuf;
  s1.wrow0[0] = 0; s1.wrow0[1] = 512; s1.wrow0[2] = 1024; s1.wrow0[3] = 1536;
  gemm_glds<4, false, true><<<16 * 392, 256, 0, stream>>>(s1, wt_all, nullptr);

  attn_mfma<<<(NBATCH * NHEADS) / 4, 256, 0, stream>>>(kbuf, qbuf, vbuf,
                                                       gbuf, a, obuf);

  GemmCfg pj = {};
  pj.A[0] = obuf; pj.bias[0] = bproj; pj.out[0] = nullptr; pj.wrow0[0] = 2048;
  gemm_glds<2, true, false><<<4 * 392, 256, 0, stream>>>(pj, wt_all,
                                                         (float*)d_out);
}

// Round 6
// 556.928 us; speedup vs baseline: 1.1299x; 1.1002x over previous
//
#include <hip/hip_runtime.h>

#define MR 50176        // B_*N = 1024*49 rows
#define DIMC 512
#define NWIN 49
#define NBATCH 1024
#define NHEADS 16
#define ATTN_SCALE 0.17677669529663689f  // 32^-0.5

typedef short bf16x8 __attribute__((ext_vector_type(8)));
typedef float f32x4 __attribute__((ext_vector_type(4)));
typedef unsigned int u32;

__device__ __forceinline__ unsigned short f2bf(float f) {
  union { float f; u32 u; } v; v.f = f;
  u32 u = v.u;
  u += 0x7FFFu + ((u >> 16) & 1u);   // round-to-nearest-even
  return (unsigned short)(u >> 16);
}
__device__ __forceinline__ float bits_f(u32 u) {
  union { u32 u; float f; } v; v.u = u; return v.f;
}

// Packed-swizzled bf16 layout (16B chunks, XOR by row&7).
__device__ __forceinline__ size_t pk_chunk(int r, int c) {
  return (((size_t)(r >> 3) * 8 + (c >> 3)) * 64 +
          ((r & 7) * 8 + ((c & 7) ^ (r & 7)))) << 4;
}

typedef const __attribute__((address_space(1))) u32* gp_t;
typedef __attribute__((address_space(3))) u32* lp_t;
__device__ __forceinline__ void glds16(const void* g, void* l) {
  __builtin_amdgcn_global_load_lds((gp_t)g, (lp_t)l, 16, 0, 0);
}

// Inline-asm global load: compiler emits NO waitcnt for it — manual counted
// vmcnt waits are the only synchronization (keeps the glds16 pipeline alive).
// Returns a true ext_vector so "=v" gets a proper aligned 4-VGPR tuple.
__device__ __forceinline__ f32x4 gload4(const float* p) {
  f32x4 r;
  asm volatile("global_load_dwordx4 %0, %1, off" : "=v"(r) : "v"(p));
  return r;
}

// ---------------------------------------------------------------------------
// 5 weight slices -> one packed bf16 [2560][512] (k,q,v,g,proj transposed).
// ---------------------------------------------------------------------------
__global__ __launch_bounds__(256) void prep_w_pack(
    const float* __restrict__ Wqkv, const float* __restrict__ Wqkv2,
    const float* __restrict__ Wgw, const float* __restrict__ Wproj,
    short* __restrict__ Wp) {
  const int tid = blockIdx.x * 256 + threadIdx.x;   // 163840 total
  const int li = tid & 63, gl = tid >> 6;
  const int kline = gl & 7, group = gl >> 3;
  const int rr = li >> 3, pp = li & 7;
  const int row = group * 8 + rr;                    // 0..2559
  const int k = kline * 64 + ((pp ^ rr) << 3);
  const int n = row & 511, mat = row >> 9;
  const float* W; int ldw, col;
  if (mat == 0)      { W = Wqkv;  ldw = 1536; col = 512 + n; }
  else if (mat == 1) { W = Wqkv2; ldw = 1536; col = n; }
  else if (mat == 2) { W = Wqkv2; ldw = 1536; col = 1024 + n; }
  else if (mat == 3) { W = Wgw;   ldw = 512;  col = n; }
  else               { W = Wproj; ldw = 512;  col = n; }
  unsigned short h[8];
#pragma unroll
  for (int j = 0; j < 8; ++j) h[j] = f2bf(W[(size_t)(k + j) * ldw + col]);
  u32 w0 = (u32)h[0] | ((u32)h[1] << 16);
  u32 w1 = (u32)h[2] | ((u32)h[3] << 16);
  u32 w2 = (u32)h[4] | ((u32)h[5] << 16);
  u32 w3 = (u32)h[6] | ((u32)h[7] << 16);
  ((uint4*)Wp)[tid] = make_uint4(w0, w1, w2, w3);
}

// ---------------------------------------------------------------------------
// Multi-output GEMM, 128x128 tile, double-buffered LDS (2 x 16KB per operand,
// 64KB total), ONE barrier per K-tile, counted vmcnt (never 0 mid-loop).
//
// CONVA steady state, iteration kt (slot s = kt&1):
//   1. issue B(kt+1) glds -> Bs[s^1]         queue: A(kt+1)8, B(kt+1)4
//   2. vmcnt(4)  (drain A(kt+1) regs only) + sched_barrier(0)
//   3. pack fp32->bf16 -> ds_write As[s^1]
//   4. issue A(kt+2) asm loads               queue: B(kt+1)4, A(kt+2)8
//   5. compute kt from As[s], Bs[s]          (B-DMA + A-loads overlap MFMA)
//   6. vmcnt(8) lgkm(0)  (drain B(kt+1); A(kt+2) stays in flight)
//   7. s_barrier
// Tails: kt==6 -> vmcnt(0) (only B(7) outstanding); kt==7 -> compute only.
// WAR safety: writes to slot s^1 always follow the barrier ending the
// compute that last read s^1.
// ---------------------------------------------------------------------------
struct GemmCfg {
  const short* A[4];
  const float* Af[4];
  const float* bias[4];
  short* out[4];
  int wrow0[4];
};

template <int LNX, bool OUT_F32, bool CONVA>
__global__ __launch_bounds__(256) void gemm_glds(
    GemmCfg cfg, const short* __restrict__ Wp, float* __restrict__ outf) {
  __shared__ short As[2][8192];   // 2 slots x 16 KB (128 rows x 64 K bf16)
  __shared__ short Bs[2][8192];   // 2 slots x 16 KB

  const int t = threadIdx.x, w = t >> 6, lane = t & 63;
  const int l15 = lane & 15, q = lane >> 4;
  const int wm = w >> 1, wn = w & 1;
  const int id = blockIdx.x;
  const int xcd = id & 7, slot = id >> 3;
  const int bx = slot & ((1 << LNX) - 1);
  const int y = xcd + ((slot >> LNX) << 3);
  const int row0 = y * 128;
  const int unit = bx >> 2, sub = bx & 3;
  const float* bias = cfg.bias[unit];
  short* outb = cfg.out[unit];
  const int nw0 = cfg.wrow0[unit] + sub * 128;
  const int col0 = sub * 128;

  f32x4 acc[4][4];
#pragma unroll
  for (int i = 0; i < 4; ++i)
#pragma unroll
    for (int j = 0; j < 4; ++j) acc[i][j] = {0.f, 0.f, 0.f, 0.f};

  const size_t lb = (size_t)lane * 16;
  const int r7 = l15 & 7, hi8 = l15 >> 3;

#define COMPUTE_TILE(SL)                                                      \
  do {                                                                        \
    _Pragma("unroll")                                                         \
    for (int sk = 0; sk < 2; ++sk) {                                          \
      const int sw = ((sk * 4 + q) ^ r7);                                     \
      const int pos = (r7 * 8 + sw) * 8;                                      \
      bf16x8 af[4], bfr[4];                                                   \
      _Pragma("unroll")                                                       \
      for (int i = 0; i < 4; ++i)                                             \
        af[i] = *(const bf16x8*)&As[SL][((wm * 8 + i * 2 + hi8) << 9) + pos]; \
      _Pragma("unroll")                                                       \
      for (int j = 0; j < 4; ++j)                                             \
        bfr[j] = *(const bf16x8*)&Bs[SL][((wn * 8 + j * 2 + hi8) << 9) + pos];\
      _Pragma("unroll")                                                       \
      for (int i = 0; i < 4; ++i)                                             \
        _Pragma("unroll")                                                     \
        for (int j = 0; j < 4; ++j)                                           \
          acc[i][j] = __builtin_amdgcn_mfma_f32_16x16x32_bf16(                \
              af[i], bfr[j], acc[i][j], 0, 0, 0);                             \
    }                                                                         \
  } while (0)

  if constexpr (CONVA) {
    const int rr = lane >> 3, pp = lane & 7;
    const float* abase =
        cfg.Af[unit] + (size_t)(row0 + w * 32 + rr) * DIMC + ((pp ^ rr) << 3);
    f32x4 ar[4][2];

    auto loadA = [&](int kt2) {
#pragma unroll
      for (int jj = 0; jj < 4; ++jj) {
        const float* s = abase + (size_t)jj * 8 * DIMC + kt2 * 64;
        ar[jj][0] = gload4(s);
        ar[jj][1] = gload4(s + 4);
      }
    };
    auto stageB = [&](int kt2) {
      const int sl = kt2 & 1;
#pragma unroll
      for (int jj = 0; jj < 4; ++jj) {
        const int rg = w * 4 + jj;
        const char* gb =
            (const char*)Wp + ((((size_t)(nw0 >> 3) + rg) * 8 + kt2) << 10);
        glds16(gb + lb, &Bs[sl][(size_t)rg << 9]);
      }
    };
    auto packA = [&](int sl) {
#pragma unroll
      for (int jj = 0; jj < 4; ++jj) {
        u32 w0 = (u32)f2bf(ar[jj][0][0]) | ((u32)f2bf(ar[jj][0][1]) << 16);
        u32 w1 = (u32)f2bf(ar[jj][0][2]) | ((u32)f2bf(ar[jj][0][3]) << 16);
        u32 w2 = (u32)f2bf(ar[jj][1][0]) | ((u32)f2bf(ar[jj][1][1]) << 16);
        u32 w3 = (u32)f2bf(ar[jj][1][2]) | ((u32)f2bf(ar[jj][1][3]) << 16);
        *(uint4*)&As[sl][(((size_t)(w * 4 + jj)) << 9) + (size_t)lane * 8] =
            make_uint4(w0, w1, w2, w3);
      }
    };

    // ---- prologue: stage tile 0, start A(1) ----
    loadA(0);                                   // queue: A0(8)
    __builtin_amdgcn_sched_barrier(0);          // pin issue order A0 < B0
    stageB(0);                                  // queue: A0(8), B0(4)
    asm volatile("s_waitcnt vmcnt(4)" ::: "memory");   // drain A0
    __builtin_amdgcn_sched_barrier(0);
    packA(0);
    loadA(1);                                   // queue: B0(4), A1(8)
    asm volatile("s_waitcnt vmcnt(8) lgkmcnt(0)" ::: "memory");  // drain B0
    asm volatile("s_barrier" ::: "memory");

    for (int kt = 0; kt < 8; ++kt) {
      const int s = kt & 1;
      if (kt < 7) {
        stageB(kt + 1);                         // queue: A(kt+1)8, B(kt+1)4
        asm volatile("s_waitcnt vmcnt(4)" ::: "memory");  // drain A(kt+1)
        __builtin_amdgcn_sched_barrier(0);
        packA(s ^ 1);
        if (kt < 6) loadA(kt + 2);              // queue: B(kt+1)4, A(kt+2)8
      }
      COMPUTE_TILE(s);
      if (kt < 6)
        asm volatile("s_waitcnt vmcnt(8) lgkmcnt(0)" ::: "memory");
      else if (kt == 6)
        asm volatile("s_waitcnt vmcnt(0) lgkmcnt(0)" ::: "memory");
      if (kt < 7) asm volatile("s_barrier" ::: "memory");
    }
  } else {
    const short* Ap = cfg.A[unit];
    auto stageAB = [&](int kt2) {
      const int sl = kt2 & 1;
#pragma unroll
      for (int jj = 0; jj < 4; ++jj) {
        const int rg = w * 4 + jj;
        const char* ga =
            (const char*)Ap + ((((size_t)(row0 >> 3) + rg) * 8 + kt2) << 10);
        glds16(ga + lb, &As[sl][(size_t)rg << 9]);
        const char* gb =
            (const char*)Wp + ((((size_t)(nw0 >> 3) + rg) * 8 + kt2) << 10);
        glds16(gb + lb, &Bs[sl][(size_t)rg << 9]);
      }
    };
    stageAB(0);
    asm volatile("s_waitcnt vmcnt(0)" ::: "memory");
    asm volatile("s_barrier" ::: "memory");
    for (int kt = 0; kt < 8; ++kt) {
      const int s = kt & 1;
      if (kt < 7) stageAB(kt + 1);      // DMA overlaps compute below
      COMPUTE_TILE(s);
      if (kt < 7) {
        asm volatile("s_waitcnt vmcnt(0) lgkmcnt(0)" ::: "memory");
        asm volatile("s_barrier" ::: "memory");
      }
    }
  }
#undef COMPUTE_TILE

#pragma unroll
  for (int j = 0; j < 4; ++j) {
    const int C = col0 + wn * 64 + j * 16 + l15;
    const float bv = bias[C];
#pragma unroll
    for (int i = 0; i < 4; ++i) {
#pragma unroll
      for (int r = 0; r < 4; ++r) {
        const int R = row0 + wm * 64 + i * 16 + q * 4 + r;
        const float val = acc[i][j][r] + bv;
        if constexpr (OUT_F32)
          outf[(size_t)R * DIMC + C] = val;
        else
          *(short*)((char*)outb + pk_chunk(R, C >> 3) + ((C & 7) << 1)) =
              (short)f2bf(val);
      }
    }
  }
}

// ---------------------------------------------------------------------------
// MFMA attention, one window per wave (unchanged; packed I/O).
// ---------------------------------------------------------------------------
__global__ __launch_bounds__(256) void attn_mfma(
    const short* __restrict__ kbuf, const short* __restrict__ qbuf,
    const short* __restrict__ vbuf, const short* __restrict__ gbuf,
    const float* __restrict__ a_scalar, short* __restrict__ obuf) {
  __shared__ short pls[4][64 * 40];
  __shared__ short vls[4][32 * 72];

  const int t = threadIdx.x;
  const int w = t >> 6, lane = t & 63;
  const int l15 = lane & 15, q = lane >> 4;
  const int wid = blockIdx.x * 4 + w;
  const int b = wid >> 4, h = wid & 15;
  const int row0 = b * NWIN;
  const float aval = a_scalar[0];
  short* P = pls[w];
  short* VT = vls[w];

#pragma unroll
  for (int it = 0; it < 5; ++it) {
    int off = (it * 64 + lane) * 8;
    if (off < 32 * 72) *(uint4*)&VT[off] = make_uint4(0u, 0u, 0u, 0u);
  }

  bf16x8 kf[4];
#pragma unroll
  for (int mj = 0; mj < 4; ++mj) {
    int m = mj * 16 + l15; if (m > 48) m = 48;
    kf[mj] = *(const bf16x8*)((const char*)kbuf + pk_chunk(row0 + m, h * 4 + q));
  }
  bf16x8 qf[4];
#pragma unroll
  for (int mi = 0; mi < 4; ++mi) {
    int n = mi * 16 + l15; if (n > 48) n = 48;
    const size_t off = pk_chunk(row0 + n, h * 4 + q);
    uint4 qa = *(const uint4*)((const char*)qbuf + off);
    uint4 ga = *(const uint4*)((const char*)gbuf + off);
    u32* qa_ = (u32*)&qa;
    u32* ga_ = (u32*)&ga;
    uint4 res; u32* r_ = (u32*)&res;
#pragma unroll
    for (int jj = 0; jj < 4; ++jj) {
      float lo = bits_f(qa_[jj] << 16) * bits_f(ga_[jj] << 16);
      float hi = bits_f(qa_[jj] & 0xffff0000u) * bits_f(ga_[jj] & 0xffff0000u);
      r_[jj] = (u32)f2bf(lo) | ((u32)f2bf(hi) << 16);
    }
    qf[mi] = *(bf16x8*)&res;
  }
#pragma unroll
  for (int it = 0; it < 4; ++it) {
    int chunk = it * 64 + lane;
    if (chunk < 196) {
      int n = chunk >> 2, dcq = chunk & 3;
      uint4 v = *(const uint4*)((const char*)vbuf + pk_chunk(row0 + n, h * 4 + dcq));
      const short* vs = (const short*)&v;
#pragma unroll
      for (int j = 0; j < 8; ++j) VT[(dcq * 8 + j) * 72 + n] = vs[j];
    }
  }

  f32x4 s[4][4];
#pragma unroll
  for (int mi = 0; mi < 4; ++mi)
#pragma unroll
    for (int nj = 0; nj < 4; ++nj) {
      f32x4 z = {0.f, 0.f, 0.f, 0.f};
      s[mi][nj] = __builtin_amdgcn_mfma_f32_16x16x32_bf16(qf[mi], kf[nj], z, 0, 0, 0);
    }

#pragma unroll
  for (int mi = 0; mi < 4; ++mi)
#pragma unroll
    for (int nj = 0; nj < 4; ++nj) {
      const bool valid = (nj * 16 + l15) < NWIN;
#pragma unroll
      for (int r = 0; r < 4; ++r)
        s[mi][nj][r] = valid ? __expf(ATTN_SCALE * s[mi][nj][r]) : 0.f;
    }

  float lsum[4][4];
#pragma unroll
  for (int mi = 0; mi < 4; ++mi)
#pragma unroll
    for (int r = 0; r < 4; ++r) {
      float part = s[mi][0][r] + s[mi][1][r] + s[mi][2][r] + s[mi][3][r];
      part += __shfl_xor(part, 1, 64);
      part += __shfl_xor(part, 2, 64);
      part += __shfl_xor(part, 4, 64);
      part += __shfl_xor(part, 8, 64);
      lsum[mi][r] = part;
    }

  f32x4 o[4][2];
#pragma unroll
  for (int mi = 0; mi < 4; ++mi)
#pragma unroll
    for (int dj = 0; dj < 2; ++dj) o[mi][dj] = {0.f, 0.f, 0.f, 0.f};

#pragma unroll
  for (int c = 0; c < 2; ++c) {
#pragma unroll
    for (int mi = 0; mi < 4; ++mi)
#pragma unroll
      for (int njh = 0; njh < 2; ++njh) {
        const int nj = c * 2 + njh;
        const int m = nj * 16 + l15;
#pragma unroll
        for (int r = 0; r < 4; ++r) {
          const int n = mi * 16 + q * 4 + r;
          float val = s[mi][nj][r];
          if (m == n) val += aval * lsum[mi][r];
          P[n * 40 + njh * 16 + l15] = (short)f2bf(val);
        }
      }
    bf16x8 bfr[2];
#pragma unroll
    for (int dj = 0; dj < 2; ++dj)
      bfr[dj] = *(const bf16x8*)&VT[(dj * 16 + l15) * 72 + c * 32 + q * 8];
#pragma unroll
    for (int mi = 0; mi < 4; ++mi) {
      bf16x8 af = *(const bf16x8*)&P[(mi * 16 + l15) * 40 + q * 8];
#pragma unroll
      for (int dj = 0; dj < 2; ++dj)
        o[mi][dj] = __builtin_amdgcn_mfma_f32_16x16x32_bf16(af, bfr[dj],
                                                            o[mi][dj], 0, 0, 0);
    }
  }

#pragma unroll
  for (int mi = 0; mi < 4; ++mi)
#pragma unroll
    for (int r = 0; r < 4; ++r) {
      const int n = mi * 16 + q * 4 + r;
      if (n < NWIN) {
        const float rl = 1.0f / lsum[mi][r];
#pragma unroll
        for (int dj = 0; dj < 2; ++dj) {
          const int d = dj * 16 + l15;
          *(short*)((char*)obuf + pk_chunk(row0 + n, h * 4 + (d >> 3)) +
                    ((d & 7) << 1)) = (short)f2bf(o[mi][dj][r] * rl);
        }
      }
    }
}

// ---------------------------------------------------------------------------
extern "C" void kernel_launch(void* const* d_in, const int* in_sizes, int n_in,
                              void* d_out, int out_size, void* d_ws,
                              size_t ws_size, hipStream_t stream) {
  const float* x     = (const float*)d_in[0];
  const float* x2    = (const float*)d_in[1];
  const float* x3    = (const float*)d_in[2];
  const float* Wqkv  = (const float*)d_in[3];
  const float* bqkv  = (const float*)d_in[4];
  const float* Wqkv2 = (const float*)d_in[5];
  const float* bqkv2 = (const float*)d_in[6];
  const float* Wgw   = (const float*)d_in[7];
  const float* bgw   = (const float*)d_in[8];
  const float* Wproj = (const float*)d_in[9];
  const float* bproj = (const float*)d_in[10];
  const float* a     = (const float*)d_in[11];

  char* ws = (char*)d_ws;
  const size_t WTSZ = (size_t)2560 * DIMC * sizeof(short);   // 2.62 MB
  const size_t BSZ  = (size_t)MR * DIMC * sizeof(short);     // 51.4 MB
  short* wt_all = (short*)ws;

  short* kbuf = (short*)(ws + WTSZ);
  short* qbuf = (short*)(ws + WTSZ + BSZ);
  short* vbuf = (short*)(ws + WTSZ + 2 * BSZ);
  short* gbuf = (short*)(ws + WTSZ + 3 * BSZ);
  short* obuf = (short*)(ws + WTSZ + 4 * BSZ);   // 259.7 MB total

  prep_w_pack<<<640, 256, 0, stream>>>(Wqkv, Wqkv2, Wgw, Wproj, wt_all);

  // Stage 1: fused fp32->bf16 conversion inside the GEMM.
  GemmCfg s1 = {};
  s1.Af[0] = x;  s1.Af[1] = x3; s1.Af[2] = x3; s1.Af[3] = x2;
  s1.bias[0] = bqkv + 512; s1.bias[1] = bqkv2;
  s1.bias[2] = bqkv2 + 1024; s1.bias[3] = bgw;
  s1.out[0] = kbuf; s1.out[1] = qbuf; s1.out[2] = vbuf; s1.out[3] = gbuf;
  s1.wrow0[0] = 0; s1.wrow0[1] = 512; s1.wrow0[2] = 1024; s1.wrow0[3] = 1536;
  gemm_glds<4, false, true><<<16 * 392, 256, 0, stream>>>(s1, wt_all, nullptr);

  attn_mfma<<<(NBATCH * NHEADS) / 4, 256, 0, stream>>>(kbuf, qbuf, vbuf,
                                                       gbuf, a, obuf);

  GemmCfg pj = {};
  pj.A[0] = obuf; pj.bias[0] = bproj; pj.out[0] = nullptr; pj.wrow0[0] = 2048;
  gemm_glds<2, true, false><<<4 * 392, 256, 0, stream>>>(pj, wt_all,
                                                         (float*)d_out);
}